// Round 9
// baseline (294.857 us; speedup 1.0000x reference)
//
#include <hip/hip_runtime.h>
#include <stdint.h>

#define S_LEN 2048
#define EMB   1024
#define NH    16
#define HD    64
#define BK 64

typedef __bf16 bf16x8 __attribute__((ext_vector_type(8)));
typedef short  short4v __attribute__((ext_vector_type(4)));
typedef unsigned int uint2v __attribute__((ext_vector_type(2)));
typedef float  floatx4 __attribute__((ext_vector_type(4)));

// Guards need compilable fallbacks: the HIP host pass reports no amdgcn builtins.
#if defined(__has_builtin)
#if __has_builtin(__builtin_amdgcn_mfma_f32_16x16x16bf16_1k)
#define HAVE_MFMA16 1
#endif
#if __has_builtin(__builtin_amdgcn_exp2f)
#define EXP2F __builtin_amdgcn_exp2f   // single v_exp_f32 — NOT ocml exp2f
#endif
#endif
#ifndef EXP2F
#define EXP2F exp2f
#endif

// 0.125 (1/sqrt(64)) * log2(e): Q pre-scale so softmax runs in exp2 domain
#define QSCALE 0.1803368801111204f

__device__ __forceinline__ unsigned short f2bf(float f) {
  unsigned u = __builtin_bit_cast(unsigned, f);
  u += 0x7fffu + ((u >> 16) & 1u);   // RNE
  return (unsigned short)(u >> 16);
}
__device__ __forceinline__ unsigned short f2bf_hu(float f) {
  return (unsigned short)((__builtin_bit_cast(unsigned, f) + 0x8000u) >> 16);
}
// pack 2 floats -> [bf16(b):bf16(a)] via v_perm, half-up
__device__ __forceinline__ unsigned packbf2(float a, float b) {
  unsigned ua = __builtin_bit_cast(unsigned, a) + 0x8000u;
  unsigned ub = __builtin_bit_cast(unsigned, b) + 0x8000u;
  return __builtin_amdgcn_perm(ub, ua, 0x07060302);
}

__global__ __launch_bounds__(256) void cvt_all(const float* __restrict__ x,
                                               const float* __restrict__ Wq,
                                               const float* __restrict__ Wk,
                                               const float* __restrict__ Wv,
                                               const float* __restrict__ Wo,
                                               unsigned short* __restrict__ xb,
                                               unsigned short* __restrict__ Wqb,
                                               unsigned short* __restrict__ Wkb,
                                               unsigned short* __restrict__ Wvb,
                                               unsigned short* __restrict__ Wob) {
  int blk = blockIdx.x;
  const float* s; unsigned short* d; int off;
  if (blk < 4096)      { s = x;  d = xb;  off = blk; }
  else if (blk < 5120) { s = Wq; d = Wqb; off = blk - 4096; }
  else if (blk < 6144) { s = Wk; d = Wkb; off = blk - 5120; }
  else if (blk < 7168) { s = Wv; d = Wvb; off = blk - 6144; }
  else                 { s = Wo; d = Wob; off = blk - 7168; }
  int i = (off * 256 + threadIdx.x) * 4;
  float4 v = *(const float4*)(s + i);
  ushort4 o;
  o.x = f2bf(v.x); o.y = f2bf(v.y); o.z = f2bf(v.z); o.w = f2bf(v.w);
  *(ushort4*)(d + i) = o;
}

__device__ __forceinline__ void stage16(const void* g, void* l) {
  __builtin_amdgcn_global_load_lds(
      (const __attribute__((address_space(1))) void*)g,
      (__attribute__((address_space(3))) void*)l, 16, 0, 0);
}

// QKV projection: 64x128 tile. Operand-swapped MFMA (C' = W x^T).
// mode 1: bf16 [B,H,S,D] (8B packed stores); mode 2: bf16 [B,H,D,S] (coalesced along s)
__global__ __launch_bounds__(256, 4) void qkv_gemm(const unsigned short* __restrict__ xb,
                                                   const unsigned short* __restrict__ Wqb,
                                                   const unsigned short* __restrict__ Wkb,
                                                   const unsigned short* __restrict__ Wvb,
                                                   const float* __restrict__ bq,
                                                   const float* __restrict__ bk,
                                                   const float* __restrict__ bv,
                                                   unsigned short* __restrict__ Qb,
                                                   unsigned short* __restrict__ Kb,
                                                   unsigned short* __restrict__ Vtb) {
  __shared__ unsigned short As[64 * BK];
  __shared__ unsigned short Bs[128 * BK];
  const int z = blockIdx.z;
  const unsigned short* Bm = (z == 0) ? Wqb : (z == 1) ? Wkb : Wvb;
  const float* bias        = (z == 0) ? bq  : (z == 1) ? bk  : bv;
  unsigned short* outp     = (z == 0) ? Qb  : (z == 1) ? Kb  : Vtb;
  const float scale = (z == 0) ? QSCALE : 1.0f;
  const int mode = (z == 2) ? 2 : 1;

  const int tid  = threadIdx.x;
  const int lane = tid & 63;
  const int wave = tid >> 6;
  const int m16  = lane & 15;
  const int quad = lane >> 4;
  const int m0 = blockIdx.x * 64;
  const int n0 = blockIdx.y * 128;
  const int wrow = (wave >> 1) * 32;
  const int wcol = (wave & 1) * 64;
  const int K = 1024;

  floatx4 acc[2][4];
  for (int i = 0; i < 2; ++i)
    for (int j = 0; j < 4; ++j) acc[i][j] = floatx4{0.f, 0.f, 0.f, 0.f};

  for (int k0 = 0; k0 < K; k0 += BK) {
    __syncthreads();
    for (int i = 0; i < 2; ++i) {
      int c = i * 256 + tid;
      int row = c >> 3, col = (c & 7) << 3;
      stage16(xb + (size_t)(m0 + row) * K + k0 + col,
              (char*)As + (size_t)(i * 256 + wave * 64) * 16);
    }
    for (int i = 0; i < 4; ++i) {
      int c = i * 256 + tid;
      int row = c >> 3, col = (c & 7) << 3;
      stage16(Bm + (size_t)(n0 + row) * K + k0 + col,
              (char*)Bs + (size_t)(i * 256 + wave * 64) * 16);
    }
    __syncthreads();
    for (int kk = 0; kk < 2; ++kk) {
      bf16x8 af[2], bfr[4];
      for (int ti = 0; ti < 2; ++ti)
        af[ti] = *(const bf16x8*)(As + (wrow + ti * 16 + m16) * BK + kk * 32 + quad * 8);
      for (int tj = 0; tj < 4; ++tj)
        bfr[tj] = *(const bf16x8*)(Bs + (wcol + tj * 16 + m16) * BK + kk * 32 + quad * 8);
      for (int ti = 0; ti < 2; ++ti)
        for (int tj = 0; tj < 4; ++tj)
          acc[ti][tj] = __builtin_amdgcn_mfma_f32_16x16x32_bf16(bfr[tj], af[ti], acc[ti][tj], 0, 0, 0);
    }
  }

  if (mode == 1) {
    for (int ti = 0; ti < 2; ++ti) {
      int m = m0 + wrow + ti * 16 + m16;
      int b = m >> 11, ss = m & 2047;
      for (int tj = 0; tj < 4; ++tj) {
        int n = n0 + wcol + tj * 16 + quad * 4;
        int hh = n >> 6, d = n & 63;
        float4 b4 = *(const float4*)(bias + n);
        float v0 = (acc[ti][tj][0] + b4.x) * scale;
        float v1 = (acc[ti][tj][1] + b4.y) * scale;
        float v2 = (acc[ti][tj][2] + b4.z) * scale;
        float v3 = (acc[ti][tj][3] + b4.w) * scale;
        uint2v pk{packbf2(v0, v1), packbf2(v2, v3)};
        *(uint2v*)((unsigned short*)outp +
                   ((size_t)(b * NH + hh) * S_LEN + ss) * HD + d) = pk;
      }
    }
  } else {
    for (int tj = 0; tj < 4; ++tj)
      for (int reg = 0; reg < 4; ++reg) {
        int n = n0 + wcol + tj * 16 + quad * 4 + reg;
        int hh = n >> 6, d = n & 63;
        float bv = bias[n];
        for (int ti = 0; ti < 2; ++ti) {
          int m = m0 + wrow + ti * 16 + m16;
          int b = m >> 11, ss = m & 2047;
          ((unsigned short*)outp)[((size_t)(b * NH + hh) * HD + d) * S_LEN + ss] =
              f2bf_hu(acc[ti][tj][reg] + bv);
        }
      }
  }
}

// Output projection: 64x64 tile; LDS 16KB, acc 16 VGPR -> 6 blocks/CU declared.
__global__ __launch_bounds__(256, 6) void out_gemm(const unsigned short* __restrict__ Ab,
                                                   const unsigned short* __restrict__ Wob,
                                                   const float* __restrict__ bo,
                                                   float* __restrict__ out) {
  __shared__ unsigned short As[64 * BK];
  __shared__ unsigned short Bs[64 * BK];
  const int tid  = threadIdx.x;
  const int lane = tid & 63;
  const int wave = tid >> 6;
  const int m16  = lane & 15;
  const int quad = lane >> 4;
  const int m0 = blockIdx.x * 64;
  const int n0 = blockIdx.y * 64;
  const int wrow = (wave >> 1) * 32;
  const int wcol = (wave & 1) * 32;
  const int K = 1024, N = 1024;

  floatx4 acc[2][2];
  for (int i = 0; i < 2; ++i)
    for (int j = 0; j < 2; ++j) acc[i][j] = floatx4{0.f, 0.f, 0.f, 0.f};

  for (int k0 = 0; k0 < K; k0 += BK) {
    __syncthreads();
    for (int i = 0; i < 2; ++i) {
      int c = i * 256 + tid;
      int row = c >> 3, col = (c & 7) << 3;
      stage16(Ab + (size_t)(m0 + row) * K + k0 + col,
              (char*)As + (size_t)(i * 256 + wave * 64) * 16);
      stage16(Wob + (size_t)(n0 + row) * K + k0 + col,
              (char*)Bs + (size_t)(i * 256 + wave * 64) * 16);
    }
    __syncthreads();
    for (int kk = 0; kk < 2; ++kk) {
      bf16x8 af[2], bfr[2];
      for (int ti = 0; ti < 2; ++ti)
        af[ti] = *(const bf16x8*)(As + (wrow + ti * 16 + m16) * BK + kk * 32 + quad * 8);
      for (int tj = 0; tj < 2; ++tj)
        bfr[tj] = *(const bf16x8*)(Bs + (wcol + tj * 16 + m16) * BK + kk * 32 + quad * 8);
      for (int ti = 0; ti < 2; ++ti)
        for (int tj = 0; tj < 2; ++tj)
          acc[ti][tj] = __builtin_amdgcn_mfma_f32_16x16x32_bf16(af[ti], bfr[tj], acc[ti][tj], 0, 0, 0);
    }
  }

  for (int tj = 0; tj < 2; ++tj) {
    int n = n0 + wcol + tj * 16 + m16;
    float bv = bo[n];
    for (int ti = 0; ti < 2; ++ti)
      for (int reg = 0; reg < 4; ++reg) {
        int m = m0 + wrow + ti * 16 + quad * 4 + reg;
        out[(size_t)m * N + n] = acc[ti][tj][reg] + bv;
      }
  }
}

// Flash attention v8: 512 thr, 128 q-rows/block, 64-kv tiles, LDS dbuf K/V
// (32 KB total -> 4 blocks/CU = 32 waves, 2x R8 occupancy; latency-bound fix).
// Fixed-reference softmax (no max/alpha), one barrier/tile, upfront mask scan.
// __launch_bounds__(512,8) pins VGPR <= 64 so occupancy is LDS/wave-slot bound.
__global__ __launch_bounds__(512, 8) void attn_kernel(const unsigned short* __restrict__ Qb,  // [B,H,S,D] *QSCALE
                                                      const unsigned short* __restrict__ Kb,  // [B,H,S,D]
                                                      const unsigned short* __restrict__ Vtb, // [B,H,D,S]
                                                      const int* __restrict__ mask,           // [B,S]
                                                      unsigned short* __restrict__ attnb) {   // [B,S,E]
  __shared__ unsigned short Ks[2 * 64 * 64];   // [p][kv][d], chunk' = chunk ^ (kv&7)
  __shared__ unsigned short Vts[2 * 64 * 64];  // [p][d][kv], chunk' = chunk ^ (d&7)
  __shared__ int zw[8];
#ifndef HAVE_MFMA16
  __shared__ unsigned short Pq[8 * 16 * 72];
#endif

  const int tid  = threadIdx.x;
  const int lane = tid & 63;
  const int wave = tid >> 6;          // 0..7
  const int m16  = lane & 15;
  const int quad = lane >> 4;
  const int bh = blockIdx.x;          // fastest -> XCD = bh % 8 (K/V L2-resident per XCD)
  const int qt = blockIdx.y;
  const int b  = bh >> 4;
  const int h  = bh & 15;
  const int q0 = qt * 128;
  const size_t head = (size_t)bh * S_LEN * HD;

  bf16x8 qf[2];
  {
    const unsigned short* qrow = Qb + head + (size_t)(q0 + wave * 16 + m16) * HD;
    qf[0] = *(const bf16x8*)(qrow + quad * 8);
    qf[1] = *(const bf16x8*)(qrow + 32 + quad * 8);
  }

  // staging: 64x64 bf16 tile = 512 chunks of 16B = 1 chunk/thread for K and V
  const int srow = tid >> 3, sch = tid & 7;
  const unsigned short* kg = Kb + head + (size_t)srow * HD + sch * 8;
  const unsigned short* vg = Vtb + head + (size_t)srow * S_LEN + sch * 8;
  const int sloff = srow * 64 + ((sch ^ (srow & 7)) << 3);
  const int* mrow = mask + b * S_LEN;

  float l_run = 0.f;
  floatx4 acc_o[4];
  for (int ti = 0; ti < 4; ++ti) acc_o[ti] = floatx4{0.f, 0.f, 0.f, 0.f};

  // one-time block-wide mask scan (2048 ints / 512 thr = 1 int4 each)
  {
    int4 mv = *(const int4*)(mrow + tid * 4);
    bool z = (mv.x & mv.y & mv.z & mv.w) == 0;   // mask values are 0/1
    unsigned long long bal = __ballot(z);
    if (lane == 0) zw[wave] = (bal != 0ull) ? 1 : 0;
  }

  // tile 0 -> LDS buf0; tile 1 -> regs
  uint4 kp = *(const uint4*)(kg);
  uint4 vp = *(const uint4*)(vg);
  *(uint4*)&Ks[sloff] = kp;
  *(uint4*)&Vts[sloff] = vp;
  kp = *(const uint4*)(kg + 64 * HD);
  vp = *(const uint4*)(vg + 64);
  __syncthreads();
  const bool anymask = (zw[0] | zw[1] | zw[2] | zw[3] | zw[4] | zw[5] | zw[6] | zw[7]) != 0;

  const int xs = m16 & 7;
  const floatx4 fz = floatx4{0.f, 0.f, 0.f, 0.f};

  for (int kb = 0; kb < 32; ++kb) {
    const int p = kb & 1;
    const unsigned short* Kp = Ks + p * (64 * 64);
    const unsigned short* Vp = Vts + p * (64 * 64);
    if (kb < 31) {
      unsigned short* Kn = Ks + (p ^ 1) * (64 * 64);
      unsigned short* Vn = Vts + (p ^ 1) * (64 * 64);
      *(uint4*)&Kn[sloff] = kp;
      *(uint4*)&Vn[sloff] = vp;
      int kvn = (kb + 2 < 32) ? (kb + 2) * 64 : 0;
      kp = *(const uint4*)(kg + (size_t)kvn * HD);
      vp = *(const uint4*)(vg + kvn);
    }

    // S^T[kv][q]: A = K fragment (m=kv), B = Q fragment (n=q); first MFMA C = const zero
    floatx4 acc_s[4];
    for (int tj = 0; tj < 4; ++tj) {
      bf16x8 kf0 = *(const bf16x8*)&Kp[(tj * 16 + m16) * 64 + ((quad ^ xs) << 3)];
      acc_s[tj] = __builtin_amdgcn_mfma_f32_16x16x32_bf16(kf0, qf[0], fz, 0, 0, 0);
    }
    for (int tj = 0; tj < 4; ++tj) {
      bf16x8 kf1 = *(const bf16x8*)&Kp[(tj * 16 + m16) * 64 + (((4 + quad) ^ xs) << 3)];
      acc_s[tj] = __builtin_amdgcn_mfma_f32_16x16x32_bf16(kf1, qf[1], acc_s[tj], 0, 0, 0);
    }

    float sv[16];
    for (int t = 0; t < 4; ++t)
      for (int r = 0; r < 4; ++r) sv[t * 4 + r] = acc_s[t][r];
    if (anymask) {
      for (int t = 0; t < 4; ++t)
        for (int r = 0; r < 4; ++r) {
          int idx = kb * 64 + t * 16 + quad * 4 + r;
          sv[t * 4 + r] += (mrow[idx] == 0) ? -1e9f : 0.f;
        }
    }

    unsigned up[8];
    float sl = 0.f;
    for (int i = 0; i < 8; ++i) {
      float p0 = EXP2F(sv[2 * i]);
      float p1 = EXP2F(sv[2 * i + 1]);
      sl += p0 + p1;
      up[i] = packbf2(p0, p1);
    }
    sl += __shfl_xor(sl, 16);
    sl += __shfl_xor(sl, 32);
    l_run += sl;

#ifdef HAVE_MFMA16
    for (int ti = 0; ti < 4; ++ti)
      for (int c = 0; c < 4; ++c) {
        short4v vf = *(const short4v*)&Vp[(ti * 16 + m16) * 64 +
                                          (((2 * c + (quad >> 1)) ^ xs) << 3) +
                                          ((quad & 1) << 2)];
        short4v Pb = __builtin_bit_cast(short4v, uint2v{up[2 * c], up[2 * c + 1]});
        acc_o[ti] = __builtin_amdgcn_mfma_f32_16x16x16bf16_1k(vf, Pb, acc_o[ti], 0, 0, 0);
      }
#else
    // host-parse / non-gfx950 fallback: per-wave LDS round-trip + x32
    unsigned short* Pw = Pq + wave * 16 * 72;
    for (int t = 0; t < 4; ++t) {
      *(unsigned*)&Pw[m16 * 72 + t * 16 + quad * 4]     = up[2 * t];
      *(unsigned*)&Pw[m16 * 72 + t * 16 + quad * 4 + 2] = up[2 * t + 1];
    }
    for (int kk = 0; kk < 2; ++kk) {
      bf16x8 pf = *(const bf16x8*)&Pw[m16 * 72 + kk * 32 + quad * 8];
      for (int ti = 0; ti < 4; ++ti) {
        bf16x8 vf = *(const bf16x8*)&Vp[(ti * 16 + m16) * 64 + (((kk * 4 + quad) ^ xs) << 3)];
        acc_o[ti] = __builtin_amdgcn_mfma_f32_16x16x32_bf16(vf, pf, acc_o[ti], 0, 0, 0);
      }
    }
#endif

    __syncthreads();
  }

  float rl = 1.f / l_run;
  int orow = q0 + wave * 16 + m16;
  for (int ti = 0; ti < 4; ++ti) {
    ushort4 o;
    o.x = f2bf_hu(acc_o[ti][0] * rl);
    o.y = f2bf_hu(acc_o[ti][1] * rl);
    o.z = f2bf_hu(acc_o[ti][2] * rl);
    o.w = f2bf_hu(acc_o[ti][3] * rl);
    int e = h * HD + ti * 16 + quad * 4;
    *(ushort4*)&attnb[((size_t)(b * S_LEN + orow)) * EMB + e] = o;
  }
}

extern "C" void kernel_launch(void* const* d_in, const int* in_sizes, int n_in,
                              void* d_out, int out_size, void* d_ws, size_t ws_size,
                              hipStream_t stream) {
  const float* x  = (const float*)d_in[0];
  const int* mask = (const int*)d_in[1];
  const float* Wq = (const float*)d_in[2];
  const float* bq = (const float*)d_in[3];
  const float* Wk = (const float*)d_in[4];
  const float* bk = (const float*)d_in[5];
  const float* Wv = (const float*)d_in[6];
  const float* bv = (const float*)d_in[7];
  const float* Wo = (const float*)d_in[8];
  const float* bo = (const float*)d_in[9];
  float* out = (float*)d_out;

  char* ws = (char*)d_ws;
  unsigned short* xb  = (unsigned short*)(ws);               // 8 MB
  unsigned short* Wqb = (unsigned short*)(ws + 8388608);     // 2 MB
  unsigned short* Wkb = (unsigned short*)(ws + 10485760);    // 2 MB
  unsigned short* Wvb = (unsigned short*)(ws + 12582912);    // 2 MB
  unsigned short* Wob = (unsigned short*)(ws + 14680064);    // 2 MB
  unsigned short* Qb  = (unsigned short*)(ws + 16777216);    // 8 MB [B,H,S,D]
  unsigned short* Kbb = (unsigned short*)(ws + 25165824);    // 8 MB [B,H,S,D]
  unsigned short* Vtb = (unsigned short*)(ws + 33554432);    // 8 MB [B,H,D,S]
  unsigned short* Ab  = (unsigned short*)(ws + 41943040);    // 8 MB [B,S,E]

  cvt_all<<<dim3(8192), dim3(256), 0, stream>>>(x, Wq, Wk, Wv, Wo, xb, Wqb, Wkb, Wvb, Wob);
  qkv_gemm<<<dim3(64, 8, 3), dim3(256), 0, stream>>>(xb, Wqb, Wkb, Wvb, bq, bk, bv, Qb, Kbb, Vtb);
  attn_kernel<<<dim3(32, 16), dim3(512), 0, stream>>>(Qb, Kbb, Vtb, mask, Ab);
  out_gemm<<<dim3(64, 16), dim3(256), 0, stream>>>(Ab, Wob, bo, out);
}

// Round 10
// 213.972 us; speedup vs baseline: 1.3780x; 1.3780x over previous
//
#include <hip/hip_runtime.h>
#include <stdint.h>

#define S_LEN 2048
#define EMB   1024
#define NH    16
#define HD    64
#define BK 64

typedef __bf16 bf16x8 __attribute__((ext_vector_type(8)));
typedef short  short4v __attribute__((ext_vector_type(4)));
typedef unsigned int uint2v __attribute__((ext_vector_type(2)));
typedef float  floatx4 __attribute__((ext_vector_type(4)));

// Guards need compilable fallbacks: the HIP host pass reports no amdgcn builtins.
#if defined(__has_builtin)
#if __has_builtin(__builtin_amdgcn_mfma_f32_16x16x16bf16_1k)
#define HAVE_MFMA16 1
#endif
#if __has_builtin(__builtin_amdgcn_exp2f)
#define EXP2F __builtin_amdgcn_exp2f   // single v_exp_f32 — NOT ocml exp2f
#endif
#endif
#ifndef EXP2F
#define EXP2F exp2f
#endif

// 0.125 (1/sqrt(64)) * log2(e): Q pre-scale so softmax runs in exp2 domain
#define QSCALE 0.1803368801111204f

__device__ __forceinline__ unsigned short f2bf(float f) {
  unsigned u = __builtin_bit_cast(unsigned, f);
  u += 0x7fffu + ((u >> 16) & 1u);   // RNE
  return (unsigned short)(u >> 16);
}
__device__ __forceinline__ unsigned short f2bf_hu(float f) {
  return (unsigned short)((__builtin_bit_cast(unsigned, f) + 0x8000u) >> 16);
}
// pack 2 floats -> [bf16(b):bf16(a)] via v_perm, half-up
__device__ __forceinline__ unsigned packbf2(float a, float b) {
  unsigned ua = __builtin_bit_cast(unsigned, a) + 0x8000u;
  unsigned ub = __builtin_bit_cast(unsigned, b) + 0x8000u;
  return __builtin_amdgcn_perm(ub, ua, 0x07060302);
}

__global__ __launch_bounds__(256) void cvt_all(const float* __restrict__ x,
                                               const float* __restrict__ Wq,
                                               const float* __restrict__ Wk,
                                               const float* __restrict__ Wv,
                                               const float* __restrict__ Wo,
                                               unsigned short* __restrict__ xb,
                                               unsigned short* __restrict__ Wqb,
                                               unsigned short* __restrict__ Wkb,
                                               unsigned short* __restrict__ Wvb,
                                               unsigned short* __restrict__ Wob) {
  int blk = blockIdx.x;
  const float* s; unsigned short* d; int off;
  if (blk < 4096)      { s = x;  d = xb;  off = blk; }
  else if (blk < 5120) { s = Wq; d = Wqb; off = blk - 4096; }
  else if (blk < 6144) { s = Wk; d = Wkb; off = blk - 5120; }
  else if (blk < 7168) { s = Wv; d = Wvb; off = blk - 6144; }
  else                 { s = Wo; d = Wob; off = blk - 7168; }
  int i = (off * 256 + threadIdx.x) * 4;
  float4 v = *(const float4*)(s + i);
  ushort4 o;
  o.x = f2bf(v.x); o.y = f2bf(v.y); o.z = f2bf(v.z); o.w = f2bf(v.w);
  *(ushort4*)(d + i) = o;
}

__device__ __forceinline__ void stage16(const void* g, void* l) {
  __builtin_amdgcn_global_load_lds(
      (const __attribute__((address_space(1))) void*)g,
      (__attribute__((address_space(3))) void*)l, 16, 0, 0);
}

// QKV projection: 64x128 tile. Operand-swapped MFMA (C' = W x^T).
// mode 1: bf16 [B,H,S,D] (8B packed stores); mode 2: bf16 [B,H,D,S] (coalesced along s)
__global__ __launch_bounds__(256, 4) void qkv_gemm(const unsigned short* __restrict__ xb,
                                                   const unsigned short* __restrict__ Wqb,
                                                   const unsigned short* __restrict__ Wkb,
                                                   const unsigned short* __restrict__ Wvb,
                                                   const float* __restrict__ bq,
                                                   const float* __restrict__ bk,
                                                   const float* __restrict__ bv,
                                                   unsigned short* __restrict__ Qb,
                                                   unsigned short* __restrict__ Kb,
                                                   unsigned short* __restrict__ Vtb) {
  __shared__ unsigned short As[64 * BK];
  __shared__ unsigned short Bs[128 * BK];
  const int z = blockIdx.z;
  const unsigned short* Bm = (z == 0) ? Wqb : (z == 1) ? Wkb : Wvb;
  const float* bias        = (z == 0) ? bq  : (z == 1) ? bk  : bv;
  unsigned short* outp     = (z == 0) ? Qb  : (z == 1) ? Kb  : Vtb;
  const float scale = (z == 0) ? QSCALE : 1.0f;
  const int mode = (z == 2) ? 2 : 1;

  const int tid  = threadIdx.x;
  const int lane = tid & 63;
  const int wave = tid >> 6;
  const int m16  = lane & 15;
  const int quad = lane >> 4;
  const int m0 = blockIdx.x * 64;
  const int n0 = blockIdx.y * 128;
  const int wrow = (wave >> 1) * 32;
  const int wcol = (wave & 1) * 64;
  const int K = 1024;

  floatx4 acc[2][4];
  for (int i = 0; i < 2; ++i)
    for (int j = 0; j < 4; ++j) acc[i][j] = floatx4{0.f, 0.f, 0.f, 0.f};

  for (int k0 = 0; k0 < K; k0 += BK) {
    __syncthreads();
    for (int i = 0; i < 2; ++i) {
      int c = i * 256 + tid;
      int row = c >> 3, col = (c & 7) << 3;
      stage16(xb + (size_t)(m0 + row) * K + k0 + col,
              (char*)As + (size_t)(i * 256 + wave * 64) * 16);
    }
    for (int i = 0; i < 4; ++i) {
      int c = i * 256 + tid;
      int row = c >> 3, col = (c & 7) << 3;
      stage16(Bm + (size_t)(n0 + row) * K + k0 + col,
              (char*)Bs + (size_t)(i * 256 + wave * 64) * 16);
    }
    __syncthreads();
    for (int kk = 0; kk < 2; ++kk) {
      bf16x8 af[2], bfr[4];
      for (int ti = 0; ti < 2; ++ti)
        af[ti] = *(const bf16x8*)(As + (wrow + ti * 16 + m16) * BK + kk * 32 + quad * 8);
      for (int tj = 0; tj < 4; ++tj)
        bfr[tj] = *(const bf16x8*)(Bs + (wcol + tj * 16 + m16) * BK + kk * 32 + quad * 8);
      for (int ti = 0; ti < 2; ++ti)
        for (int tj = 0; tj < 4; ++tj)
          acc[ti][tj] = __builtin_amdgcn_mfma_f32_16x16x32_bf16(bfr[tj], af[ti], acc[ti][tj], 0, 0, 0);
    }
  }

  if (mode == 1) {
    for (int ti = 0; ti < 2; ++ti) {
      int m = m0 + wrow + ti * 16 + m16;
      int b = m >> 11, ss = m & 2047;
      for (int tj = 0; tj < 4; ++tj) {
        int n = n0 + wcol + tj * 16 + quad * 4;
        int hh = n >> 6, d = n & 63;
        float4 b4 = *(const float4*)(bias + n);
        float v0 = (acc[ti][tj][0] + b4.x) * scale;
        float v1 = (acc[ti][tj][1] + b4.y) * scale;
        float v2 = (acc[ti][tj][2] + b4.z) * scale;
        float v3 = (acc[ti][tj][3] + b4.w) * scale;
        uint2v pk{packbf2(v0, v1), packbf2(v2, v3)};
        *(uint2v*)((unsigned short*)outp +
                   ((size_t)(b * NH + hh) * S_LEN + ss) * HD + d) = pk;
      }
    }
  } else {
    for (int tj = 0; tj < 4; ++tj)
      for (int reg = 0; reg < 4; ++reg) {
        int n = n0 + wcol + tj * 16 + quad * 4 + reg;
        int hh = n >> 6, d = n & 63;
        float bv = bias[n];
        for (int ti = 0; ti < 2; ++ti) {
          int m = m0 + wrow + ti * 16 + m16;
          int b = m >> 11, ss = m & 2047;
          ((unsigned short*)outp)[((size_t)(b * NH + hh) * HD + d) * S_LEN + ss] =
              f2bf_hu(acc[ti][tj][reg] + bv);
        }
      }
  }
}

// Output projection: 64x64 tile; LDS 16KB, acc 16 VGPR -> 6 blocks/CU declared.
__global__ __launch_bounds__(256, 6) void out_gemm(const unsigned short* __restrict__ Ab,
                                                   const unsigned short* __restrict__ Wob,
                                                   const float* __restrict__ bo,
                                                   float* __restrict__ out) {
  __shared__ unsigned short As[64 * BK];
  __shared__ unsigned short Bs[64 * BK];
  const int tid  = threadIdx.x;
  const int lane = tid & 63;
  const int wave = tid >> 6;
  const int m16  = lane & 15;
  const int quad = lane >> 4;
  const int m0 = blockIdx.x * 64;
  const int n0 = blockIdx.y * 64;
  const int wrow = (wave >> 1) * 32;
  const int wcol = (wave & 1) * 32;
  const int K = 1024, N = 1024;

  floatx4 acc[2][2];
  for (int i = 0; i < 2; ++i)
    for (int j = 0; j < 2; ++j) acc[i][j] = floatx4{0.f, 0.f, 0.f, 0.f};

  for (int k0 = 0; k0 < K; k0 += BK) {
    __syncthreads();
    for (int i = 0; i < 2; ++i) {
      int c = i * 256 + tid;
      int row = c >> 3, col = (c & 7) << 3;
      stage16(Ab + (size_t)(m0 + row) * K + k0 + col,
              (char*)As + (size_t)(i * 256 + wave * 64) * 16);
      stage16(Wob + (size_t)(n0 + row) * K + k0 + col,
              (char*)Bs + (size_t)(i * 256 + wave * 64) * 16);
    }
    __syncthreads();
    for (int kk = 0; kk < 2; ++kk) {
      bf16x8 af[2], bfr[2];
      for (int ti = 0; ti < 2; ++ti)
        af[ti] = *(const bf16x8*)(As + (wrow + ti * 16 + m16) * BK + kk * 32 + quad * 8);
      for (int tj = 0; tj < 2; ++tj)
        bfr[tj] = *(const bf16x8*)(Bs + (wcol + tj * 16 + m16) * BK + kk * 32 + quad * 8);
      for (int ti = 0; ti < 2; ++ti)
        for (int tj = 0; tj < 2; ++tj)
          acc[ti][tj] = __builtin_amdgcn_mfma_f32_16x16x32_bf16(af[ti], bfr[tj], acc[ti][tj], 0, 0, 0);
    }
  }

  for (int tj = 0; tj < 2; ++tj) {
    int n = n0 + wcol + tj * 16 + m16;
    float bv = bo[n];
    for (int ti = 0; ti < 2; ++ti)
      for (int reg = 0; reg < 4; ++reg) {
        int m = m0 + wrow + ti * 16 + quad * 4 + reg;
        out[(size_t)m * N + n] = acc[ti][tj][reg] + bv;
      }
  }
}

// Flash attention v9: 512 thr, 128 q-rows/block, 64-kv dbuf tiles (LDS 33 KB).
// __launch_bounds__(512,4): VGPR cap 128 — NO spill (R9's (512,8) cap-64 spilled
// to scratch: WRITE_SIZE 8->213 MB). Natural VGPR ~60-75 -> 3-4 blocks/CU at
// dispatch. Fixed-reference softmax, one barrier/tile, upfront mask scan,
// XOR-swizzled LDS (reg staging — global_load_lds can't scatter the swizzle).
__global__ __launch_bounds__(512, 4) void attn_kernel(const unsigned short* __restrict__ Qb,  // [B,H,S,D] *QSCALE
                                                      const unsigned short* __restrict__ Kb,  // [B,H,S,D]
                                                      const unsigned short* __restrict__ Vtb, // [B,H,D,S]
                                                      const int* __restrict__ mask,           // [B,S]
                                                      unsigned short* __restrict__ attnb) {   // [B,S,E]
  __shared__ unsigned short Ks[2 * 64 * 64];   // [p][kv][d], chunk' = chunk ^ (kv&7)
  __shared__ unsigned short Vts[2 * 64 * 64];  // [p][d][kv], chunk' = chunk ^ (d&7)
  __shared__ int zw[8];
#ifndef HAVE_MFMA16
  __shared__ unsigned short Pq[8 * 16 * 72];
#endif

  const int tid  = threadIdx.x;
  const int lane = tid & 63;
  const int wave = tid >> 6;          // 0..7
  const int m16  = lane & 15;
  const int quad = lane >> 4;
  const int bh = blockIdx.x;          // fastest -> XCD = bh % 8 (K/V L2-resident per XCD)
  const int qt = blockIdx.y;
  const int b  = bh >> 4;
  const int h  = bh & 15;
  const int q0 = qt * 128;
  const size_t head = (size_t)bh * S_LEN * HD;

  bf16x8 qf[2];
  {
    const unsigned short* qrow = Qb + head + (size_t)(q0 + wave * 16 + m16) * HD;
    qf[0] = *(const bf16x8*)(qrow + quad * 8);
    qf[1] = *(const bf16x8*)(qrow + 32 + quad * 8);
  }

  // staging: 64x64 bf16 tile = 512 chunks of 16B = 1 chunk/thread for K and V
  const int srow = tid >> 3, sch = tid & 7;
  const unsigned short* kg = Kb + head + (size_t)srow * HD + sch * 8;
  const unsigned short* vg = Vtb + head + (size_t)srow * S_LEN + sch * 8;
  const int sloff = srow * 64 + ((sch ^ (srow & 7)) << 3);
  const int* mrow = mask + b * S_LEN;

  float l_run = 0.f;
  floatx4 acc_o[4];
  for (int ti = 0; ti < 4; ++ti) acc_o[ti] = floatx4{0.f, 0.f, 0.f, 0.f};

  // one-time block-wide mask scan (2048 ints / 512 thr = 1 int4 each)
  {
    int4 mv = *(const int4*)(mrow + tid * 4);
    bool z = (mv.x & mv.y & mv.z & mv.w) == 0;   // mask values are 0/1
    unsigned long long bal = __ballot(z);
    if (lane == 0) zw[wave] = (bal != 0ull) ? 1 : 0;
  }

  // tile 0 -> LDS buf0; tile 1 -> regs
  uint4 kp = *(const uint4*)(kg);
  uint4 vp = *(const uint4*)(vg);
  *(uint4*)&Ks[sloff] = kp;
  *(uint4*)&Vts[sloff] = vp;
  kp = *(const uint4*)(kg + 64 * HD);
  vp = *(const uint4*)(vg + 64);
  __syncthreads();
  const bool anymask = (zw[0] | zw[1] | zw[2] | zw[3] | zw[4] | zw[5] | zw[6] | zw[7]) != 0;

  const int xs = m16 & 7;
  const floatx4 fz = floatx4{0.f, 0.f, 0.f, 0.f};

  for (int kb = 0; kb < 32; ++kb) {
    const int p = kb & 1;
    const unsigned short* Kp = Ks + p * (64 * 64);
    const unsigned short* Vp = Vts + p * (64 * 64);
    if (kb < 31) {
      unsigned short* Kn = Ks + (p ^ 1) * (64 * 64);
      unsigned short* Vn = Vts + (p ^ 1) * (64 * 64);
      *(uint4*)&Kn[sloff] = kp;
      *(uint4*)&Vn[sloff] = vp;
      int kvn = (kb + 2 < 32) ? (kb + 2) * 64 : 0;
      kp = *(const uint4*)(kg + (size_t)kvn * HD);
      vp = *(const uint4*)(vg + kvn);
    }

    // S^T[kv][q]: A = K fragment (m=kv), B = Q fragment (n=q); first MFMA C = const zero
    floatx4 acc_s[4];
    for (int tj = 0; tj < 4; ++tj) {
      bf16x8 kf0 = *(const bf16x8*)&Kp[(tj * 16 + m16) * 64 + ((quad ^ xs) << 3)];
      acc_s[tj] = __builtin_amdgcn_mfma_f32_16x16x32_bf16(kf0, qf[0], fz, 0, 0, 0);
    }
    for (int tj = 0; tj < 4; ++tj) {
      bf16x8 kf1 = *(const bf16x8*)&Kp[(tj * 16 + m16) * 64 + (((4 + quad) ^ xs) << 3)];
      acc_s[tj] = __builtin_amdgcn_mfma_f32_16x16x32_bf16(kf1, qf[1], acc_s[tj], 0, 0, 0);
    }

    float sv[16];
    for (int t = 0; t < 4; ++t)
      for (int r = 0; r < 4; ++r) sv[t * 4 + r] = acc_s[t][r];
    if (anymask) {
      for (int t = 0; t < 4; ++t)
        for (int r = 0; r < 4; ++r) {
          int idx = kb * 64 + t * 16 + quad * 4 + r;
          sv[t * 4 + r] += (mrow[idx] == 0) ? -1e9f : 0.f;
        }
    }

    unsigned up[8];
    float sl = 0.f;
    for (int i = 0; i < 8; ++i) {
      float p0 = EXP2F(sv[2 * i]);
      float p1 = EXP2F(sv[2 * i + 1]);
      sl += p0 + p1;
      up[i] = packbf2(p0, p1);
    }
    sl += __shfl_xor(sl, 16);
    sl += __shfl_xor(sl, 32);
    l_run += sl;

#ifdef HAVE_MFMA16
    for (int ti = 0; ti < 4; ++ti)
      for (int c = 0; c < 4; ++c) {
        short4v vf = *(const short4v*)&Vp[(ti * 16 + m16) * 64 +
                                          (((2 * c + (quad >> 1)) ^ xs) << 3) +
                                          ((quad & 1) << 2)];
        short4v Pb = __builtin_bit_cast(short4v, uint2v{up[2 * c], up[2 * c + 1]});
        acc_o[ti] = __builtin_amdgcn_mfma_f32_16x16x16bf16_1k(vf, Pb, acc_o[ti], 0, 0, 0);
      }
#else
    // host-parse / non-gfx950 fallback: per-wave LDS round-trip + x32
    unsigned short* Pw = Pq + wave * 16 * 72;
    for (int t = 0; t < 4; ++t) {
      *(unsigned*)&Pw[m16 * 72 + t * 16 + quad * 4]     = up[2 * t];
      *(unsigned*)&Pw[m16 * 72 + t * 16 + quad * 4 + 2] = up[2 * t + 1];
    }
    for (int kk = 0; kk < 2; ++kk) {
      bf16x8 pf = *(const bf16x8*)&Pw[m16 * 72 + kk * 32 + quad * 8];
      for (int ti = 0; ti < 4; ++ti) {
        bf16x8 vf = *(const bf16x8*)&Vp[(ti * 16 + m16) * 64 + (((kk * 4 + quad) ^ xs) << 3)];
        acc_o[ti] = __builtin_amdgcn_mfma_f32_16x16x32_bf16(vf, pf, acc_o[ti], 0, 0, 0);
      }
    }
#endif

    __syncthreads();
  }

  float rl = 1.f / l_run;
  int orow = q0 + wave * 16 + m16;
  for (int ti = 0; ti < 4; ++ti) {
    ushort4 o;
    o.x = f2bf_hu(acc_o[ti][0] * rl);
    o.y = f2bf_hu(acc_o[ti][1] * rl);
    o.z = f2bf_hu(acc_o[ti][2] * rl);
    o.w = f2bf_hu(acc_o[ti][3] * rl);
    int e = h * HD + ti * 16 + quad * 4;
    *(ushort4*)&attnb[((size_t)(b * S_LEN + orow)) * EMB + e] = o;
  }
}

extern "C" void kernel_launch(void* const* d_in, const int* in_sizes, int n_in,
                              void* d_out, int out_size, void* d_ws, size_t ws_size,
                              hipStream_t stream) {
  const float* x  = (const float*)d_in[0];
  const int* mask = (const int*)d_in[1];
  const float* Wq = (const float*)d_in[2];
  const float* bq = (const float*)d_in[3];
  const float* Wk = (const float*)d_in[4];
  const float* bk = (const float*)d_in[5];
  const float* Wv = (const float*)d_in[6];
  const float* bv = (const float*)d_in[7];
  const float* Wo = (const float*)d_in[8];
  const float* bo = (const float*)d_in[9];
  float* out = (float*)d_out;

  char* ws = (char*)d_ws;
  unsigned short* xb  = (unsigned short*)(ws);               // 8 MB
  unsigned short* Wqb = (unsigned short*)(ws + 8388608);     // 2 MB
  unsigned short* Wkb = (unsigned short*)(ws + 10485760);    // 2 MB
  unsigned short* Wvb = (unsigned short*)(ws + 12582912);    // 2 MB
  unsigned short* Wob = (unsigned short*)(ws + 14680064);    // 2 MB
  unsigned short* Qb  = (unsigned short*)(ws + 16777216);    // 8 MB [B,H,S,D]
  unsigned short* Kbb = (unsigned short*)(ws + 25165824);    // 8 MB [B,H,S,D]
  unsigned short* Vtb = (unsigned short*)(ws + 33554432);    // 8 MB [B,H,D,S]
  unsigned short* Ab  = (unsigned short*)(ws + 41943040);    // 8 MB [B,S,E]

  cvt_all<<<dim3(8192), dim3(256), 0, stream>>>(x, Wq, Wk, Wv, Wo, xb, Wqb, Wkb, Wvb, Wob);
  qkv_gemm<<<dim3(64, 8, 3), dim3(256), 0, stream>>>(xb, Wqb, Wkb, Wvb, bq, bk, bv, Qb, Kbb, Vtb);
  attn_kernel<<<dim3(32, 16), dim3(512), 0, stream>>>(Qb, Kbb, Vtb, mask, Ab);
  out_gemm<<<dim3(64, 16), dim3(256), 0, stream>>>(Ab, Wob, bo, out);
}